// Round 1
// baseline (107.165 us; speedup 1.0000x reference)
//
#include <hip/hip_runtime.h>

#define NB 2048

// One block per batch element. D=16, 256 threads = one thread per (i,j) output.
// ricci[i,j] = (Aprev-Acur)[i,j] - (Tprev-Tcur)[i] + sum_m Tcur[m]*G[m,i,j]
//              - sum_{k,m} G[m,i,k]*G[k,m,j]
// scalar[b]  = sum_{i,j} ricci[i,j] * inv(metric)[i,j]
__global__ __launch_bounds__(256)
void curvature_kernel(const float* __restrict__ metric,
                      const float* __restrict__ gamma,
                      float* __restrict__ out)
{
    const int b = blockIdx.x;
    const int t = threadIdx.x;
    const int i = t >> 4;
    const int j = t & 15;

    __shared__ float G[4096];            // Gamma[b]: [m][p][k] linear (16x16x16)
    __shared__ float GT[16 * 16 * 20];   // GT[m][j][k] = Gamma[k][m][j]; row stride 20 (pad: banks + 16B align)
    __shared__ float Tc[16];             // Tcur[m]
    __shared__ float aug[16][36];        // Gauss-Jordan augmented [M | I], padded stride
    __shared__ float red[4];

    const float* Gc = gamma + (size_t)b * 4096;
    const float* Gp = gamma + (size_t)((b + NB - 1) & (NB - 1)) * 4096;

    // ---- prev-batch reductions (register only; reads hit L2/L3 mostly) ----
    float aprev = 0.f, tprev = 0.f;
    #pragma unroll
    for (int k = 0; k < 16; ++k) {
        float g = Gp[k * 256 + t];       // Gamma[b-1, k, i, j], coalesced
        aprev += g;
        if (k == j) tprev = g;           // element Gamma[b-1, j, i, j] -> T[i]
    }

    // ---- cur-batch load + reductions + LDS staging (both layouts) ----
    float acur = 0.f, tcur = 0.f;
    #pragma unroll
    for (int k = 0; k < 16; ++k) {
        float g = Gc[k * 256 + t];       // Gamma[b, k, i, j], coalesced
        acur += g;
        if (k == j) tcur = g;
        G[k * 256 + t] = g;              // linear copy
        GT[i * 320 + j * 20 + k] = g;    // GT[m=i][j][k] = Gamma[k, m, j]
    }

    // reduce T over the 16 lanes of each i-group (masks <16 stay in-group)
    #pragma unroll
    for (int w = 1; w < 16; w <<= 1) {
        tprev += __shfl_xor(tprev, w);
        tcur  += __shfl_xor(tcur,  w);
    }
    if (j == 0) Tc[i] = tcur;

    // load metric into augmented GJ matrix while LDS writes drain
    aug[i][j]      = metric[(size_t)b * 256 + t];
    aug[i][16 + j] = (i == j) ? 1.f : 0.f;
    __syncthreads();

    // ---- term3 = sum_m Tcur[m] * Gamma[m,i,j] ----
    float term3 = 0.f;
    #pragma unroll
    for (int m = 0; m < 16; ++m)
        term3 += Tc[m] * G[m * 256 + t];   // consecutive lanes -> conflict-free

    // ---- term4 = sum_{m,k} Gamma[m,i,k] * Gamma[k,m,j] ----
    float term4 = 0.f;
    #pragma unroll
    for (int m = 0; m < 16; ++m) {
        const float4* xr = (const float4*)&G[m * 256 + i * 16];   // Gamma[m,i,0..15]
        const float4* yr = (const float4*)&GT[m * 320 + j * 20];  // Gamma[0..15,m,j]
        #pragma unroll
        for (int q = 0; q < 4; ++q) {
            float4 x4 = xr[q];
            float4 y4 = yr[q];
            term4 += x4.x * y4.x + x4.y * y4.y + x4.z * y4.z + x4.w * y4.w;
        }
    }

    float ricci = (aprev - acur) - (tprev - tcur) + term3 - term4;

    // ---- Gauss-Jordan inversion (SPD, eig>=1: no pivoting needed) ----
    for (int kk = 0; kk < 16; ++kk) {
        float pivinv = 1.f / aug[kk][kk];
        float f   = aug[i][kk] * pivinv;   // row factor (read before writes)
        float rk1 = aug[kk][j];
        float rk2 = aug[kk][16 + j];
        __syncthreads();
        if (i == kk) {
            aug[i][j]      = rk1 * pivinv;
            aug[i][16 + j] = rk2 * pivinv;
        } else {
            aug[i][j]      -= f * rk1;
            aug[i][16 + j] -= f * rk2;
        }
        __syncthreads();
    }

    // ---- scalar[b] = sum_t ricci * Minv[i][j], block reduction ----
    float contrib = ricci * aug[i][16 + j];
    #pragma unroll
    for (int w = 1; w < 64; w <<= 1)
        contrib += __shfl_xor(contrib, w);
    if ((t & 63) == 0) red[t >> 6] = contrib;
    __syncthreads();
    if (t == 0) out[b] = red[0] + red[1] + red[2] + red[3];
}

extern "C" void kernel_launch(void* const* d_in, const int* in_sizes, int n_in,
                              void* d_out, int out_size, void* d_ws, size_t ws_size,
                              hipStream_t stream) {
    const float* metric = (const float*)d_in[0];   // (2048, 16, 16) f32
    const float* gamma  = (const float*)d_in[1];   // (2048, 16, 16, 16) f32
    float* out = (float*)d_out;                    // (2048,) f32
    curvature_kernel<<<NB, 256, 0, stream>>>(metric, gamma, out);
}

// Round 2
// 29.294 us; speedup vs baseline: 3.6583x; 3.6583x over previous
//
#include <hip/hip_runtime.h>

#define NB 2048

// One block per batch. 256 threads; thread t = (i,j) = (t>>4, t&15).
// ricci[i,j] = (Aprev-Acur)[i,j] - (Tprev-Tcur)[i] + sum_m Tcur[m]*G[m,i,j]
//              - sum_{k,m} G[m,i,k]*G[k,m,j]
// scalar[b]  = sum_{i,j} ricci[i,j] * inv(metric)[i,j]
// Matrix inverse: wave 0 only, in-place Gauss-Jordan via shuffles (no barriers).
__global__ __launch_bounds__(256, 4)
void curvature_kernel(const float* __restrict__ metric,
                      const float* __restrict__ gamma,
                      float* __restrict__ out)
{
    const int b = blockIdx.x;
    const int t = threadIdx.x;
    const int i = t >> 4;
    const int j = t & 15;

    __shared__ float G[4096];          // natural: G[k*256 + i*16 + j] = Gamma[b,k,i,j]
    __shared__ float GT[16 * 328];     // GT[m*328 + j*20 + k] = Gamma[b,k,m,j]
    __shared__ float Tc[16];           // T[m] = sum_k Gamma[b,k,m,k]
    __shared__ float MINV[16 * 17];    // inverse metric, padded stride 17
    __shared__ float red[4];

    const float* Gc = gamma + (size_t)b * 4096;
    const float* Gp = gamma + (size_t)((b + NB - 1) & (NB - 1)) * 4096;

    // ---- prev-batch reductions (registers only; roll re-read hits L2/L3) ----
    float aprev = 0.f, tprev = 0.f;
    #pragma unroll 4
    for (int k = 0; k < 16; ++k) {
        float g = Gp[(k << 8) + t];              // coalesced
        aprev += g;
        if (k == j) tprev = g;                   // Gamma[b-1, j, i, j]
    }

    // ---- cur-batch load + reductions + LDS staging (both layouts) ----
    float acur = 0.f, tcur = 0.f;
    #pragma unroll 4
    for (int k = 0; k < 16; ++k) {
        float g = Gc[(k << 8) + t];              // coalesced
        acur += g;
        if (k == j) tcur = g;
        G[(k << 8) + t] = g;
        GT[i * 328 + j * 20 + k] = g;            // GT[m=i][j][k]
    }

    // T reduction within each 16-lane j-group
    #pragma unroll
    for (int w = 1; w < 16; w <<= 1) {
        tprev += __shfl_xor(tprev, w);
        tcur  += __shfl_xor(tcur,  w);
    }
    if (j == 0) Tc[i] = tcur;

    // wave 0 issues its metric load early (latency hides under staging)
    float4 mrow;
    if (t < 64) mrow = ((const float4*)(metric + (size_t)b * 256))[t];

    __syncthreads();   // staging (G, GT, Tc) visible to all

    // ---- wave 0: in-place Gauss-Jordan inverse, shuffle-only (SPD, no pivoting) ----
    if (t < 64) {
        const int gi = t >> 2;                   // row 0..15
        const int gq = t & 3;                    // column quad 0..3
        float a0 = mrow.x, a1 = mrow.y, a2 = mrow.z, a3 = mrow.w;
        #pragma unroll
        for (int k = 0; k < 16; ++k) {
            const int kq = k >> 2, kc = k & 3;
            float akc = (kc == 0) ? a0 : (kc == 1) ? a1 : (kc == 2) ? a2 : a3;
            float pv = __shfl(akc, (k << 2) | kq);      // pivot A[k][k]
            float f  = __shfl(akc, (t & 60) | kq);      // my row's A[i][k]
            float p0 = __shfl(a0, (k << 2) | gq);       // pivot row at my cols
            float p1 = __shfl(a1, (k << 2) | gq);
            float p2 = __shfl(a2, (k << 2) | gq);
            float p3 = __shfl(a3, (k << 2) | gq);
            float pinv = 1.0f / pv;
            bool piv = (gi == k);
            float r0 = p0 * pinv, r1 = p1 * pinv, r2 = p2 * pinv, r3 = p3 * pinv;
            a0 = piv ? r0 : fmaf(-f, r0, a0);
            a1 = piv ? r1 : fmaf(-f, r1, a1);
            a2 = piv ? r2 : fmaf(-f, r2, a2);
            a3 = piv ? r3 : fmaf(-f, r3, a3);
            if (gq == kq) {                              // column-k fixup
                float colv = piv ? pinv : -f * pinv;
                if      (kc == 0) a0 = colv;
                else if (kc == 1) a1 = colv;
                else if (kc == 2) a2 = colv;
                else              a3 = colv;
            }
        }
        MINV[gi * 17 + 4 * gq + 0] = a0;
        MINV[gi * 17 + 4 * gq + 1] = a1;
        MINV[gi * 17 + 4 * gq + 2] = a2;
        MINV[gi * 17 + 4 * gq + 3] = a3;
    }

    // ---- term3 = sum_m Tc[m] * Gamma[m,i,j] ----
    float term3 = 0.f;
    #pragma unroll 4
    for (int m = 0; m < 16; ++m)
        term3 += Tc[m] * G[(m << 8) + t];        // consecutive lanes: conflict-free

    // ---- term4 = sum_{m,k} Gamma[m,i,k] * Gamma[k,m,j] ----
    float term4 = 0.f;
    #pragma unroll 4
    for (int m = 0; m < 16; ++m) {
        const float4* xr = (const float4*)&G[(m << 8) + (i << 4)];   // Gamma[m,i,0..15]
        const float4* yr = (const float4*)&GT[m * 328 + j * 20];     // Gamma[0..15,m,j]
        #pragma unroll
        for (int q = 0; q < 4; ++q) {
            float4 x4 = xr[q];
            float4 y4 = yr[q];
            term4 += x4.x * y4.x + x4.y * y4.y + x4.z * y4.z + x4.w * y4.w;
        }
    }

    float ricci = (aprev - acur) - (tprev - tcur) + term3 - term4;

    __syncthreads();   // MINV visible

    // ---- scalar[b] = sum ricci .* Minv ----
    float contrib = ricci * MINV[i * 17 + j];
    #pragma unroll
    for (int w = 1; w < 64; w <<= 1)
        contrib += __shfl_xor(contrib, w);
    if ((t & 63) == 0) red[t >> 6] = contrib;
    __syncthreads();
    if (t == 0) out[b] = red[0] + red[1] + red[2] + red[3];
}

extern "C" void kernel_launch(void* const* d_in, const int* in_sizes, int n_in,
                              void* d_out, int out_size, void* d_ws, size_t ws_size,
                              hipStream_t stream) {
    const float* metric = (const float*)d_in[0];   // (2048, 16, 16) f32
    const float* gamma  = (const float*)d_in[1];   // (2048, 16, 16, 16) f32
    float* out = (float*)d_out;                    // (2048,) f32
    curvature_kernel<<<NB, 256, 0, stream>>>(metric, gamma, out);
}

// Round 3
// 16.912 us; speedup vs baseline: 6.3366x; 1.7321x over previous
//
#include <hip/hip_runtime.h>

#define NB 2048

typedef __attribute__((ext_vector_type(8))) short bf16x8;
typedef __attribute__((ext_vector_type(4))) float f32x4;

__device__ __forceinline__ unsigned short f2bf(float x) {
    union { float f; unsigned u; } v; v.f = x;
    return (unsigned short)((v.u + 0x7FFFu + ((v.u >> 16) & 1u)) >> 16);  // RNE
}

// One block per batch. t=(i,j)=(t>>4, t&15).
// ricci[i,j] = (Aprev-Acur)[i,j] - (Tprev-Tcur)[i] + sum_m T[m]*G[m,i,j]
//              - sum_{m,k} G[m,i,k]*G[k,m,j]
// term4 via 16x16x256 bf16 MFMA GEMM (K split over 4 waves).
// scalar[b] = sum_{i,j} ricci[i,j] * inv(metric)[i,j]  (shuffle Gauss-Jordan, wave 0)
__global__ __launch_bounds__(256, 6)
void curvature_kernel(const float* __restrict__ metric,
                      const float* __restrict__ gamma,
                      float* __restrict__ out)
{
    const int bid = blockIdx.x;
    const int b = ((bid & 7) << 8) | (bid >> 3);   // XCD swizzle: b and b-1 share an L2
    const int t = threadIdx.x;
    const int i = t >> 4;
    const int j = t & 15;

    // logical contraction index l in [0,256): m = l>>4, k = l&15
    __shared__ unsigned short XA[16][264];  // XA[i][l]  = G[l>>4, i, l&15]   (A operand)
    __shared__ unsigned short YT[16][264];  // YT[j][l]  = G[l&15, l>>4, j]   (B^T operand)
    __shared__ float P[4][16][17];          // per-wave term4 partials
    __shared__ float MINV[16 * 17];
    __shared__ float Tc[16];
    __shared__ float red[4];

    const float* Gc = gamma + (size_t)b * 4096;
    const float* Gp = gamma + (size_t)((b + NB - 1) & (NB - 1)) * 4096;

    // ---- prev-batch register reductions (roll re-read: same-XCD L2 hit) ----
    float aprev = 0.f, tprev = 0.f;
    #pragma unroll 4
    for (int k = 0; k < 16; ++k) {
        float g = Gp[(k << 8) + t];
        aprev += g;
        if (k == j) tprev = g;                  // G[b-1, j, i, j]
    }

    // ---- cur-batch load (full unroll: gc[] must stay in registers) ----
    float gc[16];
    float acur = 0.f, tcur = 0.f;
    #pragma unroll
    for (int k = 0; k < 16; ++k) {
        float g = Gc[(k << 8) + t];
        gc[k] = g;
        acur += g;
        if (k == j) tcur = g;
        XA[i][(k << 4) + j] = f2bf(g);          // A: row i, l = k*16+j  (m=k, kk=j)
    }
    // B^T: YT[j][i*16 + k] = G[k, i, j]; pack 16 bf16 -> two b128 writes
    {
        unsigned yp[8];
        #pragma unroll
        for (int k = 0; k < 16; k += 2)
            yp[k >> 1] = (unsigned)f2bf(gc[k]) | ((unsigned)f2bf(gc[k + 1]) << 16);
        uint4* dst = (uint4*)&YT[j][i << 4];
        dst[0] = make_uint4(yp[0], yp[1], yp[2], yp[3]);
        dst[1] = make_uint4(yp[4], yp[5], yp[6], yp[7]);
    }

    // T reduction within each 16-lane j-group
    #pragma unroll
    for (int w = 1; w < 16; w <<= 1) {
        tprev += __shfl_xor(tprev, w);
        tcur  += __shfl_xor(tcur,  w);
    }
    if (j == 0) Tc[i] = tcur;

    // wave 0 issues metric load early
    float4 mrow;
    if (t < 64) mrow = ((const float4*)(metric + (size_t)b * 256))[t];

    __syncthreads();   // XA, YT, Tc visible

    // ---- term4: each wave does K-steps {2w, 2w+1} of the 16x16x256 GEMM ----
    {
        const int w    = t >> 6;
        const int lane = t & 63;
        const int r    = lane & 15;     // A row / B col
        const int hi   = lane >> 4;
        f32x4 acc = {0.f, 0.f, 0.f, 0.f};
        #pragma unroll
        for (int s = 0; s < 2; ++s) {
            const int off = ((2 * w + s) << 5) + (hi << 3);   // step*32 + hi*8
            bf16x8 av = *(const bf16x8*)&XA[r][off];
            bf16x8 bv = *(const bf16x8*)&YT[r][off];
            acc = __builtin_amdgcn_mfma_f32_16x16x32_bf16(av, bv, acc, 0, 0, 0);
        }
        #pragma unroll
        for (int q = 0; q < 4; ++q)
            P[w][(hi << 2) + q][r] = acc[q];    // D: col=lane&15, row=(lane>>4)*4+q
    }

    // ---- wave 0: shuffle-only Gauss-Jordan inverse (SPD, no pivoting) ----
    if (t < 64) {
        const int gi = t >> 2;
        const int gq = t & 3;
        float a0 = mrow.x, a1 = mrow.y, a2 = mrow.z, a3 = mrow.w;
        #pragma unroll
        for (int k = 0; k < 16; ++k) {
            const int kq = k >> 2, kc = k & 3;
            float akc = (kc == 0) ? a0 : (kc == 1) ? a1 : (kc == 2) ? a2 : a3;
            float pv = __shfl(akc, (k << 2) | kq);
            float f  = __shfl(akc, (t & 60) | kq);
            float p0 = __shfl(a0, (k << 2) | gq);
            float p1 = __shfl(a1, (k << 2) | gq);
            float p2 = __shfl(a2, (k << 2) | gq);
            float p3 = __shfl(a3, (k << 2) | gq);
            float pinv = 1.0f / pv;
            bool piv = (gi == k);
            float r0 = p0 * pinv, r1 = p1 * pinv, r2 = p2 * pinv, r3 = p3 * pinv;
            a0 = piv ? r0 : fmaf(-f, r0, a0);
            a1 = piv ? r1 : fmaf(-f, r1, a1);
            a2 = piv ? r2 : fmaf(-f, r2, a2);
            a3 = piv ? r3 : fmaf(-f, r3, a3);
            if (gq == kq) {
                float colv = piv ? pinv : -f * pinv;
                if      (kc == 0) a0 = colv;
                else if (kc == 1) a1 = colv;
                else if (kc == 2) a2 = colv;
                else              a3 = colv;
            }
        }
        MINV[gi * 17 + 4 * gq + 0] = a0;
        MINV[gi * 17 + 4 * gq + 1] = a1;
        MINV[gi * 17 + 4 * gq + 2] = a2;
        MINV[gi * 17 + 4 * gq + 3] = a3;
    }

    // ---- term3 from registers ----
    float term3 = 0.f;
    #pragma unroll
    for (int m = 0; m < 16; ++m)
        term3 = fmaf(Tc[m], gc[m], term3);

    __syncthreads();   // P, MINV visible

    float term4 = P[0][i][j] + P[1][i][j] + P[2][i][j] + P[3][i][j];
    float ricci = (aprev - acur) - (tprev - tcur) + term3 - term4;

    float contrib = ricci * MINV[i * 17 + j];
    #pragma unroll
    for (int w = 1; w < 64; w <<= 1)
        contrib += __shfl_xor(contrib, w);
    if ((t & 63) == 0) red[t >> 6] = contrib;
    __syncthreads();
    if (t == 0) out[b] = red[0] + red[1] + red[2] + red[3];
}

extern "C" void kernel_launch(void* const* d_in, const int* in_sizes, int n_in,
                              void* d_out, int out_size, void* d_ws, size_t ws_size,
                              hipStream_t stream) {
    const float* metric = (const float*)d_in[0];   // (2048, 16, 16) f32
    const float* gamma  = (const float*)d_in[1];   // (2048, 16, 16, 16) f32
    float* out = (float*)d_out;                    // (2048,) f32
    curvature_kernel<<<NB, 256, 0, stream>>>(metric, gamma, out);
}

// Round 4
// 16.761 us; speedup vs baseline: 6.3938x; 1.0090x over previous
//
#include <hip/hip_runtime.h>
#include <hip/hip_bf16.h>

#define NB 2048

typedef __attribute__((ext_vector_type(8))) short bf16x8;
typedef __attribute__((ext_vector_type(4))) float f32x4;

// One block per batch. Thread t owns Gamma row (k,i) = G[b, k, i, 0..15].
// scalar[b] = <Aprev-Acur, Minv> - sum_i dT[i]*R[i] + sum_m T[m]*Q[m] - <term4, Minv>
//   A[p,q]=sum_k G[k,p,q]; T[m]=sum_k G[k,m,k]; R[i]=sum_j Minv[i,j];
//   Q[m]=<G[m,:,:],Minv>; term4[i,j]=sum_{m,k} G[m,i,k]*G[k,m,j] (bf16 MFMA).
// All terms are per-thread partial dots with Minv -> one block reduction.
__global__ __launch_bounds__(256, 6)
void curvature_kernel(const float* __restrict__ metric,
                      const float* __restrict__ gamma,
                      float* __restrict__ out)
{
    const int bid = blockIdx.x;
    const int b = ((bid & 7) << 8) | (bid >> 3);   // XCD swizzle: b, b-1 share an L2
    const int t = threadIdx.x;
    const int wv = t >> 6;
    const int lane = t & 63;
    const int ku = t >> 4;                          // my Gamma plane k
    const int iu = t & 15;                          // my Gamma row i
    const int gjw = b & 3;                          // GJ wave: spread across SIMDs

    __shared__ alignas(16) unsigned short XA[16][264];  // XA[i][m*16+k] = G[m,i,k]
    __shared__ alignas(16) unsigned short YT[16][264];  // YT[j][m*16+k] = G[k,m,j]
    __shared__ alignas(16) float P[4][16][17];          // per-wave term4 partials
    __shared__ alignas(16) float MINV[16][20];
    __shared__ alignas(16) float TT[16][20];            // TT[m][k] = G[k,m,k]
    __shared__ float Tc[16];
    __shared__ float red[4];

    const float* Gc = gamma + (size_t)b * 4096;
    const float* Gp = gamma + (size_t)((b + NB - 1) & (NB - 1)) * 4096;

    // ---- issue all global loads up front (independent) ----
    const float4* gc4 = (const float4*)(Gc + (t << 4));
    const float4* gp4 = (const float4*)(Gp + (t << 4));
    float4 g0 = gc4[0], g1 = gc4[1], g2 = gc4[2], g3 = gc4[3];
    float4 p0 = gp4[0], p1 = gp4[1], p2 = gp4[2], p3 = gp4[3];
    float gku = Gc[(t << 4) + ku];     // G[b,  ku, iu, ku]  (L1 hit)
    float pku = Gp[(t << 4) + ku];     // G[b-1,ku, iu, ku]
    float4 mrow;
    if (wv == gjw) mrow = ((const float4*)(metric + (size_t)b * 256))[lane];

    float gr[16], d[16];
    gr[0]=g0.x; gr[1]=g0.y; gr[2]=g0.z; gr[3]=g0.w;
    gr[4]=g1.x; gr[5]=g1.y; gr[6]=g1.z; gr[7]=g1.w;
    gr[8]=g2.x; gr[9]=g2.y; gr[10]=g2.z; gr[11]=g2.w;
    gr[12]=g3.x; gr[13]=g3.y; gr[14]=g3.z; gr[15]=g3.w;
    d[0]=p0.x-gr[0]; d[1]=p0.y-gr[1]; d[2]=p0.z-gr[2]; d[3]=p0.w-gr[3];
    d[4]=p1.x-gr[4]; d[5]=p1.y-gr[5]; d[6]=p1.z-gr[6]; d[7]=p1.w-gr[7];
    d[8]=p2.x-gr[8]; d[9]=p2.y-gr[9]; d[10]=p2.z-gr[10]; d[11]=p2.w-gr[11];
    d[12]=p3.x-gr[12]; d[13]=p3.y-gr[13]; d[14]=p3.z-gr[14]; d[15]=p3.w-gr[15];
    const float dt = pku - gku;        // Tprev[iu] - Tcur[iu] partial (plane ku)

    // ---- stage bf16 operands (native cvt, packed) ----
    unsigned yp[8];
    #pragma unroll
    for (int q = 0; q < 8; ++q) {
        union { __hip_bfloat162 h; unsigned u; } cv;
        cv.h = __float22bfloat162_rn(make_float2(gr[2*q], gr[2*q+1]));
        yp[q] = cv.u;
    }
    uint4* xdst = (uint4*)&XA[iu][ku << 4];         // contiguous row chunk
    xdst[0] = make_uint4(yp[0], yp[1], yp[2], yp[3]);
    xdst[1] = make_uint4(yp[4], yp[5], yp[6], yp[7]);
    #pragma unroll
    for (int q = 0; q < 8; ++q) {                    // transposed scatter
        YT[2*q  ][(iu << 4) + ku] = (unsigned short)(yp[q] & 0xffffu);
        YT[2*q+1][(iu << 4) + ku] = (unsigned short)(yp[q] >> 16);
    }
    TT[iu][ku] = gku;
    __syncthreads();

    // ---- term4: 16x16x256 GEMM, K-steps {2wv, 2wv+1} per wave ----
    {
        const int r = lane & 15, hi = lane >> 4;
        f32x4 acc = {0.f, 0.f, 0.f, 0.f};
        #pragma unroll
        for (int s = 0; s < 2; ++s) {
            const int off = ((2 * wv + s) << 5) + (hi << 3);
            bf16x8 av = *(const bf16x8*)&XA[r][off];
            bf16x8 bv = *(const bf16x8*)&YT[r][off];
            acc = __builtin_amdgcn_mfma_f32_16x16x32_bf16(av, bv, acc, 0, 0, 0);
        }
        #pragma unroll
        for (int q = 0; q < 4; ++q)
            P[wv][(hi << 2) + q][r] = acc[q];        // D: col=lane&15, row=4*hi+q
    }

    // ---- Tc[m] = sum_k TT[m][k] (one idle wave, 16 lanes) ----
    if (wv == ((gjw + 1) & 3) && lane < 16) {
        const float4* tr = (const float4*)&TT[lane][0];
        float4 a = tr[0], c = tr[1], e = tr[2], f = tr[3];
        Tc[lane] = ((a.x + a.y) + (a.z + a.w)) + ((c.x + c.y) + (c.z + c.w))
                 + ((e.x + e.y) + (e.z + e.w)) + ((f.x + f.y) + (f.z + f.w));
    }

    // ---- GJ wave: shuffle-only Gauss-Jordan inverse (SPD, no pivot) ----
    if (wv == gjw) {
        const int gi = lane >> 2;
        const int gq = lane & 3;
        float a0 = mrow.x, a1 = mrow.y, a2 = mrow.z, a3 = mrow.w;
        #pragma unroll
        for (int k = 0; k < 16; ++k) {
            const int kq = k >> 2, kc = k & 3;
            float akc = (kc == 0) ? a0 : (kc == 1) ? a1 : (kc == 2) ? a2 : a3;
            float pv = __shfl(akc, (k << 2) | kq);
            float f  = __shfl(akc, (lane & 60) | kq);
            float q0 = __shfl(a0, (k << 2) | gq);
            float q1 = __shfl(a1, (k << 2) | gq);
            float q2 = __shfl(a2, (k << 2) | gq);
            float q3 = __shfl(a3, (k << 2) | gq);
            float pinv = 1.0f / pv;
            bool piv = (gi == k);
            float r0 = q0 * pinv, r1 = q1 * pinv, r2 = q2 * pinv, r3 = q3 * pinv;
            a0 = piv ? r0 : fmaf(-f, r0, a0);
            a1 = piv ? r1 : fmaf(-f, r1, a1);
            a2 = piv ? r2 : fmaf(-f, r2, a2);
            a3 = piv ? r3 : fmaf(-f, r3, a3);
            if (gq == kq) {
                float colv = piv ? pinv : -f * pinv;
                if      (kc == 0) a0 = colv;
                else if (kc == 1) a1 = colv;
                else if (kc == 2) a2 = colv;
                else              a3 = colv;
            }
        }
        MINV[gi][4 * gq + 0] = a0;
        MINV[gi][4 * gq + 1] = a1;
        MINV[gi][4 * gq + 2] = a2;
        MINV[gi][4 * gq + 3] = a3;
    }
    __syncthreads();

    // ---- epilogue: per-thread partial dots with Minv ----
    float mr[16];
    {
        const float4* mv = (const float4*)&MINV[iu][0];
        float4 m0 = mv[0], m1 = mv[1], m2 = mv[2], m3 = mv[3];
        mr[0]=m0.x; mr[1]=m0.y; mr[2]=m0.z; mr[3]=m0.w;
        mr[4]=m1.x; mr[5]=m1.y; mr[6]=m1.z; mr[7]=m1.w;
        mr[8]=m2.x; mr[9]=m2.y; mr[10]=m2.z; mr[11]=m2.w;
        mr[12]=m3.x; mr[13]=m3.y; mr[14]=m3.z; mr[15]=m3.w;
    }
    float s1 = 0.f, qd = 0.f, R = 0.f;
    #pragma unroll
    for (int j = 0; j < 16; ++j) {
        s1 = fmaf(d[j], mr[j], s1);     // <dA, Minv> partial
        qd = fmaf(gr[j], mr[j], qd);    // Q[ku] partial
        R += mr[j];                     // R[iu]
    }
    float s4 = (P[0][ku][iu] + P[1][ku][iu] + P[2][ku][iu] + P[3][ku][iu])
               * MINV[iu][ku];          // Minv symmetric: Minv[ku][iu]
    float s = s1 - dt * R + Tc[ku] * qd - s4;

    #pragma unroll
    for (int w2 = 1; w2 < 64; w2 <<= 1)
        s += __shfl_xor(s, w2);
    if (lane == 0) red[wv] = s;
    __syncthreads();
    if (t == 0) out[b] = (red[0] + red[1]) + (red[2] + red[3]);
}

extern "C" void kernel_launch(void* const* d_in, const int* in_sizes, int n_in,
                              void* d_out, int out_size, void* d_ws, size_t ws_size,
                              hipStream_t stream) {
    const float* metric = (const float*)d_in[0];   // (2048, 16, 16) f32
    const float* gamma  = (const float*)d_in[1];   // (2048, 16, 16, 16) f32
    float* out = (float*)d_out;                    // (2048,) f32
    curvature_kernel<<<NB, 256, 0, stream>>>(metric, gamma, out);
}